// Round 3
// baseline (678.810 us; speedup 1.0000x reference)
//
#include <hip/hip_runtime.h>

// ---------------------------------------------------------------------------
// GatingNetworkWithTopK: h = relu(x@W1+b1); g = softmax(h@W2+b2);
// top-1 mask; out = masked / (colsum+1e-4) * 32768
//
// Numerics: split-bf16 (hi+lo), 3-product MFMA (verified: absmax 0.25 vs
// threshold 149.76). R3: 4x2 wave tile (128x64), BK=16, triple-buffered LDS,
// raw vmcnt(6) waits (never drain the pipe), perfect-spread XOR bank swizzle.
// ---------------------------------------------------------------------------

typedef float f32x4 __attribute__((ext_vector_type(4)));
typedef float f32x16 __attribute__((ext_vector_type(16)));
typedef __bf16 bf16x8 __attribute__((ext_vector_type(8)));
typedef unsigned short u16x4 __attribute__((ext_vector_type(4)));

#define NTOK 32768
#define DIN 1024
#define DH 2048
#define NE 16

__device__ __forceinline__ unsigned short f2bf(float f) {
  unsigned u = __float_as_uint(f);
  u += 0x7FFFu + ((u >> 16) & 1u);
  return (unsigned short)(u >> 16);
}
__device__ __forceinline__ float bf2f(unsigned short s) {
  return __uint_as_float(((unsigned)s) << 16);
}

__device__ __forceinline__ void async16(const void* g, void* s) {
  __builtin_amdgcn_global_load_lds((const __attribute__((address_space(1))) void*)g,
                                   (__attribute__((address_space(3))) void*)s, 16, 0, 0);
}

#define WAIT6_BAR() asm volatile("s_waitcnt vmcnt(6)\n\ts_barrier" ::: "memory")
#define WAIT0_BAR() asm volatile("s_waitcnt vmcnt(0)\n\ts_barrier" ::: "memory")

// ------------------- merged preprocessing (one launch) ----------------------
// blocks [0,32768): split x -> xhi/xlo
// blocks [32768,34816): transpose+split W1 -> whi/wlo [N][K]
// blocks [34816,34832): W2 -> MFMA-B-fragment order hi/lo
__global__ void prep_k(const float* __restrict__ x, const float* __restrict__ W1,
                       const float* __restrict__ W2, unsigned short* __restrict__ xhi,
                       unsigned short* __restrict__ xlo, unsigned short* __restrict__ whi,
                       unsigned short* __restrict__ wlo, unsigned short* __restrict__ w2fh,
                       unsigned short* __restrict__ w2fl) {
  __shared__ float tile[32][33];
  const int b = blockIdx.x;
  if (b < 32768) {
    size_t i = (size_t)b * 256 + threadIdx.x;
    f32x4 v = ((const f32x4*)x)[i];
    u16x4 h, l;
#pragma unroll
    for (int j = 0; j < 4; ++j) {
      unsigned short hh = f2bf(v[j]);
      h[j] = hh;
      l[j] = f2bf(v[j] - bf2f(hh));
    }
    ((u16x4*)xhi)[i] = h;
    ((u16x4*)xlo)[i] = l;
  } else if (b < 34816) {
    const int v = b - 32768;
    const int nt = v & 63, kt = v >> 6;
    const int c = threadIdx.x & 31, r0 = threadIdx.x >> 5;
#pragma unroll
    for (int i = 0; i < 4; ++i) {
      int k = (kt << 5) + r0 + (i << 3);
      tile[r0 + (i << 3)][c] = W1[(size_t)k * DH + (nt << 5) + c];
    }
    __syncthreads();
#pragma unroll
    for (int i = 0; i < 4; ++i) {
      int n = (nt << 5) + r0 + (i << 3);
      float vv = tile[c][r0 + (i << 3)];
      unsigned short hh = f2bf(vv);
      whi[(size_t)n * DIN + (kt << 5) + c] = hh;
      wlo[(size_t)n * DIN + (kt << 5) + c] = f2bf(vv - bf2f(hh));
    }
  } else {
    const int t = (b - 34816) * 256 + threadIdx.x;  // 0..4095
    const int kstep = t >> 6, l = t & 63;
    const int q = l >> 4, e = l & 15;
    u16x4 h0, h1, l0, l1;
#pragma unroll
    for (int j = 0; j < 8; ++j) {
      float v = W2[(size_t)((kstep << 5) + (q << 3) + j) * NE + e];
      unsigned short hh = f2bf(v);
      unsigned short ll = f2bf(v - bf2f(hh));
      if (j < 4) { h0[j] = hh; l0[j] = ll; } else { h1[j - 4] = hh; l1[j - 4] = ll; }
    }
    ((u16x4*)w2fh)[t * 2] = h0;
    ((u16x4*)w2fh)[t * 2 + 1] = h1;
    ((u16x4*)w2fl)[t * 2] = l0;
    ((u16x4*)w2fl)[t * 2 + 1] = l1;
  }
}

// ------------------------- fused GEMM1 + partial logits ---------------------
// Block tile 256(tokens) x 128(cols), 4 waves 2x2, wave tile 128x64 (4x2 of
// 32x32x16 MFMA, 3 split-products). BK=16. LDS buf (24KB) = 384 rows
// (A 0..255, B 256..383) x 4 chunks of 16B; stored chunk = logical ^ (row&3)
// (perfect 8-round bank spread for wave64 b128 reads). Triple-buffered,
// prefetch distance 2, per-wave vmcnt(6) waits.
struct Stg {
  const unsigned short* gp[6];
  int loff[6];
};

__device__ __forceinline__ void stage(const Stg& s, int kt, unsigned char* smem, int bufoff) {
#pragma unroll
  for (int i = 0; i < 6; ++i) async16(s.gp[i] + (kt << 4), smem + bufoff + s.loff[i]);
}

__device__ __forceinline__ void compute(const unsigned char* smem, int bufoff,
                                        f32x16 (&acc)[4][2], int warow, int wacol, int la,
                                        int half) {
  const unsigned char* sA = smem + bufoff;
  const unsigned char* sB = smem + bufoff + 16384;
  bf16x8 ah[4], al[4], bh[2], bl[2];
#pragma unroll
  for (int u = 0; u < 4; ++u) {
    const int r = warow + (u << 5) + la;
    ah[u] = *(const bf16x8*)(sA + (r << 6) + ((half ^ (r & 3)) << 4));
    al[u] = *(const bf16x8*)(sA + (r << 6) + (((2 + half) ^ (r & 3)) << 4));
  }
#pragma unroll
  for (int v = 0; v < 2; ++v) {
    const int r = wacol + (v << 5) + la;
    bh[v] = *(const bf16x8*)(sB + (r << 6) + ((half ^ (r & 3)) << 4));
    bl[v] = *(const bf16x8*)(sB + (r << 6) + (((2 + half) ^ (r & 3)) << 4));
  }
#pragma unroll
  for (int i = 0; i < 4; ++i)
#pragma unroll
    for (int j = 0; j < 2; ++j) {
      acc[i][j] = __builtin_amdgcn_mfma_f32_32x32x16_bf16(ah[i], bh[j], acc[i][j], 0, 0, 0);
      acc[i][j] = __builtin_amdgcn_mfma_f32_32x32x16_bf16(ah[i], bl[j], acc[i][j], 0, 0, 0);
      acc[i][j] = __builtin_amdgcn_mfma_f32_32x32x16_bf16(al[i], bh[j], acc[i][j], 0, 0, 0);
    }
}

__global__ __launch_bounds__(256, 2) void gemm1_fused_k(
    const unsigned short* __restrict__ xhi, const unsigned short* __restrict__ xlo,
    const unsigned short* __restrict__ whi, const unsigned short* __restrict__ wlo,
    const unsigned short* __restrict__ w2fh, const unsigned short* __restrict__ w2fl,
    const float* __restrict__ b1, float* __restrict__ plog) {
  __shared__ unsigned char smem[73728];  // 3 x 24576; epilogue reuses [0,34816)
  const int t = threadIdx.x;
  const int w = t >> 6, l = t & 63, la = l & 31, half = l >> 5;
  const int rowBase = blockIdx.y << 8;  // 256 tokens per block
  const int colBase = blockIdx.x << 7;  // 128 cols per block
  const int warow = (w >> 1) << 7;      // 0 or 128
  const int wacol = (w & 1) << 6;       // 0 or 64

  Stg s;
#pragma unroll
  for (int i = 0; i < 6; ++i) {
    const int c = (i << 8) + t;  // 0..1535
    const int row = c >> 2;
    const int lc = (c & 3) ^ (row & 3);
    const int plane = lc >> 1, kh = lc & 1;
    if (row < 256)
      s.gp[i] = (plane ? xlo : xhi) + (size_t)(rowBase + row) * DIN + (kh << 3);
    else
      s.gp[i] = (plane ? wlo : whi) + (size_t)(colBase + row - 256) * DIN + (kh << 3);
    s.loff[i] = c << 4;
  }

  f32x16 acc[4][2] = {};

  stage(s, 0, smem, 0);
  stage(s, 1, smem, 24576);
  WAIT6_BAR();
#pragma unroll 1
  for (int kt = 0; kt < 63; kt += 3) {
    stage(s, kt + 2, smem, 49152);
    compute(smem, 0, acc, warow, wacol, la, half);
    WAIT6_BAR();
    stage(s, kt + 3 > 63 ? 63 : kt + 3, smem, 0);
    compute(smem, 24576, acc, warow, wacol, la, half);
    WAIT6_BAR();
    stage(s, kt + 4 > 63 ? 63 : kt + 4, smem, 24576);
    compute(smem, 49152, acc, warow, wacol, la, half);
    WAIT6_BAR();
  }
  compute(smem, 0, acc, warow, wacol, la, half);  // tile 63 (63%3==0)
  WAIT0_BAR();  // drain redundant clamp loads before LDS reuse

  // ---- epilogue: bias + relu (exact fp32 h lives in acc) ----
  float b1v[2];
#pragma unroll
  for (int j = 0; j < 2; ++j) b1v[j] = b1[colBase + wacol + (j << 5) + la];
#pragma unroll
  for (int i = 0; i < 4; ++i)
#pragma unroll
    for (int j = 0; j < 2; ++j)
#pragma unroll
      for (int r = 0; r < 16; ++r) acc[i][j][r] = fmaxf(acc[i][j][r] + b1v[j], 0.0f);

  const int q16 = l >> 4, e16 = l & 15;
  const int myhalf = warow >> 7;

#pragma unroll
  for (int hh = 0; hh < 2; ++hh) {
    f32x4 pacc[2] = {};
#pragma unroll
    for (int p = 0; p < 2; ++p) {
      if (myhalf == hh) {
#pragma unroll
        for (int i = 0; i < 4; ++i)
#pragma unroll
          for (int j = 0; j < 2; ++j)
#pragma unroll
            for (int r = 0; r < 16; ++r) {
              const int rowl = (i << 5) + (r & 3) + ((r >> 2) << 3) + (half << 2);
              const int coll = wacol + (j << 5) + la;
              const float v = acc[i][j][r];
              const unsigned short sv = (p == 0) ? f2bf(v) : f2bf(v - bf2f(f2bf(v)));
              *(unsigned short*)(smem + rowl * 272 + (coll << 1)) = sv;
            }
      }
      __syncthreads();
#pragma unroll
      for (int tm = 0; tm < 2; ++tm) {
        const int tokl = ((w * 2 + tm) << 4) + e16;  // 0..127
#pragma unroll
        for (int ss = 0; ss < 4; ++ss) {
          bf16x8 a = *(const bf16x8*)(smem + tokl * 272 + (ss << 6) + (q16 << 4));
          const size_t gs = (size_t)(((colBase >> 5) + ss) << 6);
          bf16x8 vbh = *(const bf16x8*)(w2fh + ((gs + l) << 3));
          pacc[tm] = __builtin_amdgcn_mfma_f32_16x16x32_bf16(a, vbh, pacc[tm], 0, 0, 0);
          if (p == 0) {
            bf16x8 vbl = *(const bf16x8*)(w2fl + ((gs + l) << 3));
            pacc[tm] = __builtin_amdgcn_mfma_f32_16x16x32_bf16(a, vbl, pacc[tm], 0, 0, 0);
          }
        }
      }
      __syncthreads();
    }
    // store this half's partial logits: plog[bx][token][e]
#pragma unroll
    for (int tm = 0; tm < 2; ++tm)
#pragma unroll
      for (int r = 0; r < 4; ++r) {
        const int tokl = (hh << 7) + (((w * 2 + tm) << 4)) + (q16 << 2) + r;
        plog[((size_t)blockIdx.x << 19) + ((size_t)(rowBase + tokl) << 4) + e16] = pacc[tm][r];
      }
  }
}

// ----------------- reduce partials + softmax + argmax + denom ---------------
__global__ void reduce_softmax_k(const float* __restrict__ plog, const float* __restrict__ b2,
                                 int* __restrict__ top1, float* __restrict__ pval,
                                 float* __restrict__ denom) {
  const int tok = blockIdx.x * 256 + threadIdx.x;
  float lg[16];
#pragma unroll
  for (int e = 0; e < 16; ++e) lg[e] = b2[e];
  for (int p = 0; p < 16; ++p) {
    const f32x4* q = (const f32x4*)(plog + ((size_t)p << 19) + ((size_t)tok << 4));
#pragma unroll
    for (int g = 0; g < 4; ++g) {
      f32x4 v = q[g];
      lg[g * 4 + 0] += v[0];
      lg[g * 4 + 1] += v[1];
      lg[g * 4 + 2] += v[2];
      lg[g * 4 + 3] += v[3];
    }
  }
  float m = lg[0];
  int idx = 0;
#pragma unroll
  for (int e = 1; e < 16; ++e)
    if (lg[e] > m) { m = lg[e]; idx = e; }
  float se = 0.0f;
#pragma unroll
  for (int e = 0; e < 16; ++e) se += expf(lg[e] - m);
  const float pt = 1.0f / se;

  __shared__ float sden[16];
  if (threadIdx.x < 16) sden[threadIdx.x] = 0.0f;
  __syncthreads();
  atomicAdd(&sden[idx], pt);
  __syncthreads();
  if (threadIdx.x < 16) atomicAdd(&denom[threadIdx.x], sden[threadIdx.x]);
  top1[tok] = idx;
  pval[tok] = pt;
}

// ------------------------------- finalize -----------------------------------
__global__ void finalize_k(const int* __restrict__ top1, const float* __restrict__ pval,
                           const float* __restrict__ denom, float* __restrict__ out) {
  const int tok = blockIdx.x * 256 + threadIdx.x;
  const int e0 = top1[tok];
  const float v = pval[tok] / (denom[e0] + 1e-4f) * 32768.0f;
  f32x4* q = (f32x4*)(out + ((size_t)tok << 4));
#pragma unroll
  for (int g = 0; g < 4; ++g) {
    f32x4 o;
#pragma unroll
    for (int j = 0; j < 4; ++j) o[j] = ((g * 4 + j) == e0) ? v : 0.0f;
    q[g] = o;
  }
}

// ---------------------------------------------------------------------------
extern "C" void kernel_launch(void* const* d_in, const int* in_sizes, int n_in, void* d_out,
                              int out_size, void* d_ws, size_t ws_size, hipStream_t stream) {
  (void)in_sizes; (void)n_in; (void)out_size; (void)ws_size;
  const float* x = (const float*)d_in[0];
  const float* W1 = (const float*)d_in[1];
  const float* b1 = (const float*)d_in[2];
  const float* W2 = (const float*)d_in[3];
  const float* b2 = (const float*)d_in[4];
  float* out = (float*)d_out;

  char* p = (char*)d_ws;
  unsigned short* xhi = (unsigned short*)p; p += (size_t)NTOK * DIN * 2;
  unsigned short* xlo = (unsigned short*)p; p += (size_t)NTOK * DIN * 2;
  unsigned short* whi = (unsigned short*)p; p += (size_t)DH * DIN * 2;
  unsigned short* wlo = (unsigned short*)p; p += (size_t)DH * DIN * 2;
  unsigned short* w2fh = (unsigned short*)p; p += (size_t)64 * 64 * 8 * 2;
  unsigned short* w2fl = (unsigned short*)p; p += (size_t)64 * 64 * 8 * 2;
  float* plog = (float*)p; p += (size_t)16 * NTOK * NE * 4;
  int* top1 = (int*)p; p += (size_t)NTOK * 4;
  float* pval = (float*)p; p += (size_t)NTOK * 4;
  float* denom = (float*)p; p += 256;

  hipMemsetAsync(denom, 0, 256, stream);
  prep_k<<<34832, 256, 0, stream>>>(x, W1, W2, xhi, xlo, whi, wlo, w2fh, w2fl);
  gemm1_fused_k<<<dim3(16, 128), 256, 0, stream>>>(xhi, xlo, whi, wlo, w2fh, w2fl, b1, plog);
  reduce_softmax_k<<<128, 256, 0, stream>>>(plog, b2, top1, pval, denom);
  finalize_k<<<128, 256, 0, stream>>>(top1, pval, denom, out);
}

// Round 5
// 643.627 us; speedup vs baseline: 1.0547x; 1.0547x over previous
//
#include <hip/hip_runtime.h>

// ---------------------------------------------------------------------------
// GatingNetworkWithTopK: h = relu(x@W1+b1); g = softmax(h@W2+b2);
// top-1 mask; out = masked / (colsum+1e-4) * 32768
//
// Numerics: split-bf16 (hi+lo), 3-product MFMA (verified R1-R3: absmax 0.25
// vs threshold 149.76). R4 (recompile of R4 design; R4 itself was a compile
// error -- vector-element ref binding):
//  - fixed LDS swizzle for 64-B rows: sc = (lc + (r>>1)) & 3  (R3's lc^(r&3)
//    hit only 4/8 bank groups per 32-lane phase -> 2x conflicts)
//  - x hi/lo split fused into gemm (kills 268 MB prep traffic): fp32 x ->
//    VGPR -> truncation split -> ds_write_b128, 2-body pipeline depth
//  - barriers: s_waitcnt vmcnt(6) lgkmcnt(0) (6 = exactly this body's vm ops)
// ---------------------------------------------------------------------------

typedef float f32x4 __attribute__((ext_vector_type(4)));
typedef float f32x16 __attribute__((ext_vector_type(16)));
typedef __bf16 bf16x8 __attribute__((ext_vector_type(8)));
typedef unsigned short u16x4 __attribute__((ext_vector_type(4)));
typedef unsigned int u32x4 __attribute__((ext_vector_type(4)));

#define NTOK 32768
#define DIN 1024
#define DH 2048
#define NE 16

__device__ __forceinline__ unsigned short f2bf(float f) {
  unsigned u = __float_as_uint(f);
  u += 0x7FFFu + ((u >> 16) & 1u);
  return (unsigned short)(u >> 16);
}
__device__ __forceinline__ float bf2f(unsigned short s) {
  return __uint_as_float(((unsigned)s) << 16);
}

__device__ __forceinline__ void async16(const void* g, void* s) {
  __builtin_amdgcn_global_load_lds((const __attribute__((address_space(1))) void*)g,
                                   (__attribute__((address_space(3))) void*)s, 16, 0, 0);
}

// per-body barrier: exactly 6 vm events issued per body (2 B-async + 4 A-load),
// so vmcnt(6) == "all previous bodies' loads complete" regardless of in-body
// scheduling. lgkmcnt(0) drains our ds_writes.
#define WAIT6_BAR() asm volatile("s_waitcnt vmcnt(6) lgkmcnt(0)\n\ts_barrier" ::: "memory")
#define WAIT0_BAR() asm volatile("s_waitcnt vmcnt(0) lgkmcnt(0)\n\ts_barrier" ::: "memory")

// truncation split of a float pair into packed bf16 hi / lo words.
// hi = top 16 bits (remainder captured exactly); lo = top 16 bits of r.
struct SplitPair { unsigned h, l; };
__device__ __forceinline__ SplitPair split_pair(float a, float b) {
  unsigned ua = __float_as_uint(a), ub = __float_as_uint(b);
  unsigned hab = ua & 0xFFFF0000u, hbb = ub & 0xFFFF0000u;
  float ra = a - __uint_as_float(hab);
  float rb = b - __uint_as_float(hbb);
  SplitPair o;
  o.h = (ua >> 16) | hbb;
  o.l = (__float_as_uint(ra) >> 16) | (__float_as_uint(rb) & 0xFFFF0000u);
  return o;
}

// ------------------- preprocessing: W1 transpose+split, W2 frags ------------
__global__ void prep_k(const float* __restrict__ W1, const float* __restrict__ W2,
                       unsigned short* __restrict__ whi, unsigned short* __restrict__ wlo,
                       unsigned short* __restrict__ w2fh, unsigned short* __restrict__ w2fl) {
  __shared__ float tile[32][33];
  const int b = blockIdx.x;
  if (b < 2048) {
    const int nt = b & 63, kt = b >> 6;
    const int c = threadIdx.x & 31, r0 = threadIdx.x >> 5;
#pragma unroll
    for (int i = 0; i < 4; ++i) {
      int k = (kt << 5) + r0 + (i << 3);
      tile[r0 + (i << 3)][c] = W1[(size_t)k * DH + (nt << 5) + c];
    }
    __syncthreads();
#pragma unroll
    for (int i = 0; i < 4; ++i) {
      int n = (nt << 5) + r0 + (i << 3);
      float vv = tile[c][r0 + (i << 3)];
      unsigned short hh = f2bf(vv);
      whi[(size_t)n * DIN + (kt << 5) + c] = hh;
      wlo[(size_t)n * DIN + (kt << 5) + c] = f2bf(vv - bf2f(hh));
    }
  } else {
    const int t = (b - 2048) * 256 + threadIdx.x;  // 0..4095
    const int kstep = t >> 6, l = t & 63;
    const int q = l >> 4, e = l & 15;
    u16x4 h0, h1, l0, l1;
#pragma unroll
    for (int j = 0; j < 8; ++j) {
      float v = W2[(size_t)((kstep << 5) + (q << 3) + j) * NE + e];
      unsigned short hh = f2bf(v);
      unsigned short ll = f2bf(v - bf2f(hh));
      if (j < 4) { h0[j] = hh; l0[j] = ll; } else { h1[j - 4] = hh; l1[j - 4] = ll; }
    }
    ((u16x4*)w2fh)[t * 2] = h0;
    ((u16x4*)w2fh)[t * 2 + 1] = h1;
    ((u16x4*)w2fl)[t * 2] = l0;
    ((u16x4*)w2fl)[t * 2 + 1] = l1;
  }
}

// ------------------------- fused GEMM1 + partial logits ---------------------
// Block tile 256(tok) x 128(col), 4 waves 2x2, wave tile 128x64. BK=16.
// LDS buffer 24KB = A region (256 rows x 64B) + B region (128 rows x 64B).
// Row = 4 chunks of 16B; stored chunk sc = (lc + (row>>1)) & 3, lc: 0=hi k0-7,
// 1=hi k8-15, 2=lo k0-7, 3=lo k8-15. Triple-buffered.
// A staged via fp32 VGPR loads + in-register split; B via global_load_lds.

struct StgB {
  const unsigned short* gp[2];
  int loff[2];
};

__device__ __forceinline__ void stage_B(const StgB& s, int kt, unsigned char* smem, int bufoff) {
#pragma unroll
  for (int i = 0; i < 2; ++i) async16(s.gp[i] + (kt << 4), smem + bufoff + s.loff[i]);
}

__device__ __forceinline__ void loadA(const float* xrow, int kt, f32x4 (&r)[4]) {
  const f32x4* p = (const f32x4*)(xrow + (kt << 4));
#pragma unroll
  for (int q = 0; q < 4; ++q) r[q] = p[q];
}

__device__ __forceinline__ void convertA(const f32x4 (&r)[4], unsigned char* smem, int bufoff,
                                         int t) {
  unsigned char* arow = smem + bufoff + (t << 6);
  const int t2 = (t >> 1) & 3;
#pragma unroll
  for (int c2 = 0; c2 < 2; ++c2) {
    u32x4 H, L;
    const f32x4 v0 = r[(c2 << 1)];
    const f32x4 v1 = r[(c2 << 1) + 1];
    SplitPair p0 = split_pair(v0[0], v0[1]);
    SplitPair p1 = split_pair(v0[2], v0[3]);
    SplitPair p2 = split_pair(v1[0], v1[1]);
    SplitPair p3 = split_pair(v1[2], v1[3]);
    H[0] = p0.h; L[0] = p0.l;
    H[1] = p1.h; L[1] = p1.l;
    H[2] = p2.h; L[2] = p2.l;
    H[3] = p3.h; L[3] = p3.l;
    const int sc = (c2 + t2) & 3;
    *(u32x4*)(arow + (sc << 4)) = H;
    *(u32x4*)(arow + ((sc ^ 2) << 4)) = L;
  }
}

__device__ __forceinline__ void compute(const unsigned char* smem, int bufoff,
                                        f32x16 (&acc)[4][2], int warow, int wacol, int la,
                                        int half) {
  const unsigned char* sA = smem + bufoff;
  const unsigned char* sB = smem + bufoff + 16384;
  bf16x8 ah[4], al[4], bh[2], bl[2];
#pragma unroll
  for (int u = 0; u < 4; ++u) {
    const int r = warow + (u << 5) + la;
    const int s0 = (half + (r >> 1)) & 3;
    ah[u] = *(const bf16x8*)(sA + (r << 6) + (s0 << 4));
    al[u] = *(const bf16x8*)(sA + (r << 6) + ((s0 ^ 2) << 4));
  }
#pragma unroll
  for (int v = 0; v < 2; ++v) {
    const int r = wacol + (v << 5) + la;
    const int s0 = (half + (r >> 1)) & 3;
    bh[v] = *(const bf16x8*)(sB + (r << 6) + (s0 << 4));
    bl[v] = *(const bf16x8*)(sB + (r << 6) + ((s0 ^ 2) << 4));
  }
#pragma unroll
  for (int i = 0; i < 4; ++i)
#pragma unroll
    for (int j = 0; j < 2; ++j) {
      acc[i][j] = __builtin_amdgcn_mfma_f32_32x32x16_bf16(ah[i], bh[j], acc[i][j], 0, 0, 0);
      acc[i][j] = __builtin_amdgcn_mfma_f32_32x32x16_bf16(ah[i], bl[j], acc[i][j], 0, 0, 0);
      acc[i][j] = __builtin_amdgcn_mfma_f32_32x32x16_bf16(al[i], bh[j], acc[i][j], 0, 0, 0);
    }
}

__global__ __launch_bounds__(256, 2) void gemm1_fused_k(
    const float* __restrict__ x, const unsigned short* __restrict__ whi,
    const unsigned short* __restrict__ wlo, const unsigned short* __restrict__ w2fh,
    const unsigned short* __restrict__ w2fl, const float* __restrict__ b1,
    float* __restrict__ plog) {
  __shared__ unsigned char smem[73728];  // 3 x 24576; epilogue reuses [0,34816)
  const int t = threadIdx.x;
  const int w = t >> 6, l = t & 63, la = l & 31, half = l >> 5;
  const int rowBase = blockIdx.y << 8;  // 256 tokens per block
  const int colBase = blockIdx.x << 7;  // 128 cols per block
  const int warow = (w >> 1) << 7;
  const int wacol = (w & 1) << 6;

  StgB s;
#pragma unroll
  for (int i = 0; i < 2; ++i) {
    const int c = (i << 8) + t;  // 0..511
    const int rr = c >> 2, sc = c & 3;
    const int lc = (sc - (rr >> 1)) & 3;
    s.gp[i] = ((lc >> 1) ? wlo : whi) + (size_t)(colBase + rr) * DIN + ((lc & 1) << 3);
    s.loff[i] = 16384 + (c << 4);
  }
  const float* xrow = x + (size_t)(rowBase + t) * DIN;

  f32x16 acc[4][2] = {};
  f32x4 rA[4], rB[4];

  // prologue
  loadA(xrow, 0, rA);
  stage_B(s, 0, smem, 0);
  stage_B(s, 1, smem, 24576);
  convertA(rA, smem, 0, t);  // compiler waits on rA loads only
  loadA(xrow, 1, rA);
  loadA(xrow, 2, rB);
  WAIT0_BAR();

  int oa = 0, ob = 24576, oc = 49152;
#pragma unroll 1
  for (int kt = 0; kt < 64; kt += 2) {
    // body kt: compute(buf oa), stage B(kt+2)->oc, write A(kt+1)->ob
    stage_B(s, kt + 2 > 63 ? 63 : kt + 2, smem, oc);
    convertA(rA, smem, ob, t);  // A(kt+1)
    loadA(xrow, kt + 3 > 63 ? 63 : kt + 3, rA);
    compute(smem, oa, acc, warow, wacol, la, half);
    WAIT6_BAR();
    { int tmp = oa; oa = ob; ob = oc; oc = tmp; }
    // body kt+1
    stage_B(s, kt + 3 > 63 ? 63 : kt + 3, smem, oc);
    convertA(rB, smem, ob, t);  // A(kt+2)
    loadA(xrow, kt + 4 > 63 ? 63 : kt + 4, rB);
    compute(smem, oa, acc, warow, wacol, la, half);
    WAIT6_BAR();
    { int tmp = oa; oa = ob; ob = oc; oc = tmp; }
  }
  WAIT0_BAR();  // full drain before epilogue LDS reuse

  // ---- epilogue: bias + relu (exact fp32 h lives in acc) ----
  float b1v[2];
#pragma unroll
  for (int j = 0; j < 2; ++j) b1v[j] = b1[colBase + wacol + (j << 5) + la];
#pragma unroll
  for (int i = 0; i < 4; ++i)
#pragma unroll
    for (int j = 0; j < 2; ++j)
#pragma unroll
      for (int r = 0; r < 16; ++r) acc[i][j][r] = fmaxf(acc[i][j][r] + b1v[j], 0.0f);

  const int q16 = l >> 4, e16 = l & 15;
  const int myhalf = warow >> 7;

#pragma unroll
  for (int hh = 0; hh < 2; ++hh) {
    f32x4 pacc[2] = {};
#pragma unroll
    for (int p = 0; p < 2; ++p) {
      if (myhalf == hh) {
#pragma unroll
        for (int i = 0; i < 4; ++i)
#pragma unroll
          for (int j = 0; j < 2; ++j)
#pragma unroll
            for (int r = 0; r < 16; ++r) {
              const int rowl = (i << 5) + (r & 3) + ((r >> 2) << 3) + (half << 2);
              const int coll = wacol + (j << 5) + la;
              const float v = acc[i][j][r];
              const unsigned short sv = (p == 0) ? f2bf(v) : f2bf(v - bf2f(f2bf(v)));
              *(unsigned short*)(smem + rowl * 272 + (coll << 1)) = sv;
            }
      }
      __syncthreads();
#pragma unroll
      for (int tm = 0; tm < 2; ++tm) {
        const int tokl = ((w * 2 + tm) << 4) + e16;  // 0..127
#pragma unroll
        for (int ss = 0; ss < 4; ++ss) {
          bf16x8 a = *(const bf16x8*)(smem + tokl * 272 + (ss << 6) + (q16 << 4));
          const size_t gs = (size_t)(((colBase >> 5) + ss) << 6);
          bf16x8 vbh = *(const bf16x8*)(w2fh + ((gs + l) << 3));
          pacc[tm] = __builtin_amdgcn_mfma_f32_16x16x32_bf16(a, vbh, pacc[tm], 0, 0, 0);
          if (p == 0) {
            bf16x8 vbl = *(const bf16x8*)(w2fl + ((gs + l) << 3));
            pacc[tm] = __builtin_amdgcn_mfma_f32_16x16x32_bf16(a, vbl, pacc[tm], 0, 0, 0);
          }
        }
      }
      __syncthreads();
    }
#pragma unroll
    for (int tm = 0; tm < 2; ++tm)
#pragma unroll
      for (int r = 0; r < 4; ++r) {
        const int tokl = (hh << 7) + (((w * 2 + tm) << 4)) + (q16 << 2) + r;
        plog[((size_t)blockIdx.x << 19) + ((size_t)(rowBase + tokl) << 4) + e16] = pacc[tm][r];
      }
  }
}

// ----------------- reduce partials + softmax + argmax + denom ---------------
__global__ void reduce_softmax_k(const float* __restrict__ plog, const float* __restrict__ b2,
                                 int* __restrict__ top1, float* __restrict__ pval,
                                 float* __restrict__ denom) {
  const int tok = blockIdx.x * 256 + threadIdx.x;
  float lg[16];
#pragma unroll
  for (int e = 0; e < 16; ++e) lg[e] = b2[e];
  for (int p = 0; p < 16; ++p) {
    const f32x4* q = (const f32x4*)(plog + ((size_t)p << 19) + ((size_t)tok << 4));
#pragma unroll
    for (int g = 0; g < 4; ++g) {
      f32x4 v = q[g];
      lg[g * 4 + 0] += v[0];
      lg[g * 4 + 1] += v[1];
      lg[g * 4 + 2] += v[2];
      lg[g * 4 + 3] += v[3];
    }
  }
  float m = lg[0];
  int idx = 0;
#pragma unroll
  for (int e = 1; e < 16; ++e)
    if (lg[e] > m) { m = lg[e]; idx = e; }
  float se = 0.0f;
#pragma unroll
  for (int e = 0; e < 16; ++e) se += expf(lg[e] - m);
  const float pt = 1.0f / se;

  __shared__ float sden[16];
  if (threadIdx.x < 16) sden[threadIdx.x] = 0.0f;
  __syncthreads();
  atomicAdd(&sden[idx], pt);
  __syncthreads();
  if (threadIdx.x < 16) atomicAdd(&denom[threadIdx.x], sden[threadIdx.x]);
  top1[tok] = idx;
  pval[tok] = pt;
}

// ------------------------------- finalize -----------------------------------
__global__ void finalize_k(const int* __restrict__ top1, const float* __restrict__ pval,
                           const float* __restrict__ denom, float* __restrict__ out) {
  const int tok = blockIdx.x * 256 + threadIdx.x;
  const int e0 = top1[tok];
  const float v = pval[tok] / (denom[e0] + 1e-4f) * 32768.0f;
  f32x4* q = (f32x4*)(out + ((size_t)tok << 4));
#pragma unroll
  for (int g = 0; g < 4; ++g) {
    f32x4 o;
#pragma unroll
    for (int j = 0; j < 4; ++j) o[j] = ((g * 4 + j) == e0) ? v : 0.0f;
    q[g] = o;
  }
}

// ---------------------------------------------------------------------------
extern "C" void kernel_launch(void* const* d_in, const int* in_sizes, int n_in, void* d_out,
                              int out_size, void* d_ws, size_t ws_size, hipStream_t stream) {
  (void)in_sizes; (void)n_in; (void)out_size; (void)ws_size;
  const float* x = (const float*)d_in[0];
  const float* W1 = (const float*)d_in[1];
  const float* b1 = (const float*)d_in[2];
  const float* W2 = (const float*)d_in[3];
  const float* b2 = (const float*)d_in[4];
  float* out = (float*)d_out;

  char* p = (char*)d_ws;
  unsigned short* whi = (unsigned short*)p; p += (size_t)DH * DIN * 2;
  unsigned short* wlo = (unsigned short*)p; p += (size_t)DH * DIN * 2;
  unsigned short* w2fh = (unsigned short*)p; p += (size_t)64 * 64 * 8 * 2;
  unsigned short* w2fl = (unsigned short*)p; p += (size_t)64 * 64 * 8 * 2;
  float* plog = (float*)p; p += (size_t)16 * NTOK * NE * 4;
  int* top1 = (int*)p; p += (size_t)NTOK * 4;
  float* pval = (float*)p; p += (size_t)NTOK * 4;
  float* denom = (float*)p; p += 256;

  (void)hipMemsetAsync(denom, 0, 256, stream);
  prep_k<<<2064, 256, 0, stream>>>(W1, W2, whi, wlo, w2fh, w2fl);
  gemm1_fused_k<<<dim3(16, 128), 256, 0, stream>>>(x, whi, wlo, w2fh, w2fl, b1, plog);
  reduce_softmax_k<<<128, 256, 0, stream>>>(plog, b2, top1, pval, denom);
  finalize_k<<<128, 256, 0, stream>>>(top1, pval, denom, out);
}